// Round 6
// baseline (192.571 us; speedup 1.0000x reference)
//
#include <hip/hip_runtime.h>

#define NBLK 256

// tanh(x) = 1 - 2/(exp(2x)+1); exp(2x) = exp2(x * 2*log2(e)).
// Overflow -> inf -> rcp(inf)=0 -> 1; underflow -> -1. abs err ~3e-7.
__device__ __forceinline__ float fast_tanh(float x) {
    float e = __builtin_amdgcn_exp2f(x * 2.885390082f);
    return 1.0f - 2.0f * __builtin_amdgcn_rcpf(e + 1.0f);
}

// One hidden layer, in place: (h, dh) <- tanh-prop of (h, dh) through W, b.
// W, b point at GLOBAL memory; every index is a compile-time constant and the
// pointers are uniform kernel args -> the compiler scalarizes these loads to
// s_load (SGPR broadcast), and v_fmac_f32 consumes the weight as its one
// legal SGPR operand. Zero LDS traffic in the hot loop. k-outer / j-inner
// ordering makes each k read one contiguous 20-float row (wide s_load_dwordxN)
// and keeps only ~20 weight SGPRs live at a time.
__device__ __forceinline__ void layer(const float* __restrict__ W,
                                      const float* __restrict__ b,
                                      float (&h)[20], float (&dh)[20]) {
    float a[20], d[20];
#pragma unroll
    for (int j = 0; j < 20; ++j) { a[j] = b[j]; d[j] = 0.0f; }
#pragma unroll
    for (int k = 0; k < 20; ++k) {
        const float hk = h[k], dk = dh[k];
#pragma unroll
        for (int j = 0; j < 20; ++j) {
            const float w = W[k * 20 + j];     // uniform -> SGPR
            a[j] += hk * w;
            d[j] += dk * w;
        }
    }
#pragma unroll
    for (int j = 0; j < 20; ++j) {
        const float e = fast_tanh(a[j]);
        h[j]  = e;
        dh[j] = (1.0f - e * e) * d[j];
    }
}

// Single-arg launch_bounds ONLY: explicit min-waves hints forced sub-footprint
// VGPR budgets and spilled state to scratch (R3: 4.3 GB HBM; R4: 0.9 GB).
__global__ __launch_bounds__(NBLK) void pinn_kernel(
    const float* __restrict__ T,
    const float* __restrict__ W1, const float* __restrict__ b1,
    const float* __restrict__ W2, const float* __restrict__ b2,
    const float* __restrict__ W3, const float* __restrict__ b3,
    const float* __restrict__ W4, const float* __restrict__ b4,
    const float* __restrict__ Wo, const float* __restrict__ bo,
    const float* __restrict__ C1, const float* __restrict__ C2, const float* __restrict__ C3,
    float* __restrict__ out, int n)
{
    const int i = blockIdx.x * NBLK + threadIdx.x;
    if (i >= n) return;

    const float t = T[i];

    float h[20], dh[20];

    // ---- layer 1: z = t*W1 + b1, dz = W1 (tangent dt = 1) ----
#pragma unroll
    for (int j = 0; j < 20; ++j) {
        const float w = W1[j];                 // uniform -> SGPR
        const float e = fast_tanh(t * w + b1[j]);
        h[j]  = e;
        dh[j] = (1.0f - e * e) * w;
    }

    // ---- layers 2..4 ----
    layer(W2, b2, h, dh);
    layer(W3, b3, h, dh);
    layer(W4, b4, h, dh);

    // ---- output layer: o_j = bo[j] + sum_k h[k]*Wo[k][j] ----
    float o0 = bo[0], o1 = bo[1], o2 = bo[2];
    float q0 = 0.f,   q1 = 0.f,   q2 = 0.f;
#pragma unroll
    for (int k = 0; k < 20; ++k) {
        const float w0 = Wo[k * 3 + 0], w1 = Wo[k * 3 + 1], w2 = Wo[k * 3 + 2];
        const float hk = h[k], dk = dh[k];
        o0 += hk * w0; o1 += hk * w1; o2 += hk * w2;
        q0 += dk * w0; q1 += dk * w1; q2 += dk * w2;
    }

    const float x = o0, y = o1, zz = o2;
    const float c1 = C1[0], c2 = C2[0], c3 = C3[0];

    const float fx = q0 - c1 * (y - x);
    const float fy = q1 - x * (c2 - zz) + y;
    const float fz = q2 - x * y + c3 * zz;

    // out[i*6 + {0..5}]; 24*i bytes is 8B-aligned -> three float2 stores
    float2* po = reinterpret_cast<float2*>(out + (size_t)i * 6);
    po[0] = make_float2(x,  y);
    po[1] = make_float2(zz, fx);
    po[2] = make_float2(fy, fz);
}

extern "C" void kernel_launch(void* const* d_in, const int* in_sizes, int n_in,
                              void* d_out, int out_size, void* d_ws, size_t ws_size,
                              hipStream_t stream) {
    const float* T  = (const float*)d_in[0];
    const float* W1 = (const float*)d_in[1];
    const float* b1 = (const float*)d_in[2];
    const float* W2 = (const float*)d_in[3];
    const float* b2 = (const float*)d_in[4];
    const float* W3 = (const float*)d_in[5];
    const float* b3 = (const float*)d_in[6];
    const float* W4 = (const float*)d_in[7];
    const float* b4 = (const float*)d_in[8];
    const float* Wo = (const float*)d_in[9];
    const float* bo = (const float*)d_in[10];
    const float* C1 = (const float*)d_in[11];
    const float* C2 = (const float*)d_in[12];
    const float* C3 = (const float*)d_in[13];
    float* out = (float*)d_out;

    const int n = in_sizes[0];
    const int blocks = (n + NBLK - 1) / NBLK;
    pinn_kernel<<<blocks, NBLK, 0, stream>>>(T, W1, b1, W2, b2, W3, b3, W4, b4,
                                             Wo, bo, C1, C2, C3, out, n);
}